// Round 1
// baseline (1016.799 us; speedup 1.0000x reference)
//
#include <hip/hip_runtime.h>
#include <math.h>

#define NN 100000

// ---------------------------------------------------------------------------
// Edge scatter: for edge (a,b), contribution c = (x[b]-x[a]) * (s[b]-s[a])
// is the same vector for BOTH endpoints (both factors flip sign).
// ---------------------------------------------------------------------------
__global__ void edge_scatter_kernel(const float* __restrict__ x,
                                    const float* __restrict__ s,
                                    const int* __restrict__ ei,
                                    float* __restrict__ Z,
                                    int E) {
    int i = blockIdx.x * blockDim.x + threadIdx.x;
    int stride = gridDim.x * blockDim.x;
    for (; i < E; i += stride) {
        int a = ei[i];
        int b = ei[i + E];
        float ds = s[b] - s[a];
        float cx = (x[3 * b + 0] - x[3 * a + 0]) * ds;
        float cy = (x[3 * b + 1] - x[3 * a + 1]) * ds;
        float cz = (x[3 * b + 2] - x[3 * a + 2]) * ds;
        atomicAdd(&Z[3 * a + 0], cx);
        atomicAdd(&Z[3 * a + 1], cy);
        atomicAdd(&Z[3 * a + 2], cz);
        atomicAdd(&Z[3 * b + 0], cx);
        atomicAdd(&Z[3 * b + 1], cy);
        atomicAdd(&Z[3 * b + 2], cz);
    }
}

// ---------------------------------------------------------------------------
// Per-node: cos between y[v] and Z[v]; accumulate masked loss / angle / count.
// ---------------------------------------------------------------------------
__global__ void node_reduce_kernel(const float* __restrict__ y,
                                   const float* __restrict__ Z,
                                   const unsigned char* __restrict__ mask,
                                   float* __restrict__ acc,
                                   int N) {
    int i = blockIdx.x * blockDim.x + threadIdx.x;
    float l = 0.f, a = 0.f, c = 0.f;
    if (i < N) {
        float yx = y[3 * i + 0], yy = y[3 * i + 1], yz = y[3 * i + 2];
        float zx = Z[3 * i + 0], zy = Z[3 * i + 1], zz = Z[3 * i + 2];
        float ny = sqrtf(yx * yx + yy * yy + yz * yz);
        float nz = sqrtf(zx * zx + zy * zy + zz * zz);
        float cosv = (yx * zx + yy * zy + yz * zz) / (ny * nz);
        float m = mask[i] ? 1.f : 0.f;
        l = m * (1.f - fabsf(cosv));
        float cc = fminf(fmaxf(cosv, -1.f), 1.f);
        a = m * acosf(cc) * 57.295779513082320876f;  // degrees
        c = m;
    }
    // wave-64 reduction
    #pragma unroll
    for (int off = 32; off > 0; off >>= 1) {
        l += __shfl_down(l, off);
        a += __shfl_down(a, off);
        c += __shfl_down(c, off);
    }
    if ((threadIdx.x & 63) == 0) {
        atomicAdd(&acc[0], l);
        atomicAdd(&acc[1], a);
        atomicAdd(&acc[2], c);
    }
}

__global__ void finalize_kernel(const float* __restrict__ acc,
                                float* __restrict__ out) {
    float cnt = fmaxf(acc[2], 1.f);
    out[0] = acc[0] / cnt;   // loss
    out[1] = acc[1] / cnt;   // avg angle (degrees)
}

extern "C" void kernel_launch(void* const* d_in, const int* in_sizes, int n_in,
                              void* d_out, int out_size, void* d_ws, size_t ws_size,
                              hipStream_t stream) {
    const float*         x    = (const float*)d_in[0];
    const float*         y    = (const float*)d_in[1];
    const float*         s    = (const float*)d_in[2];
    const int*           ei   = (const int*)d_in[3];
    const unsigned char* mask = (const unsigned char*)d_in[4];
    float*               out  = (float*)d_out;

    const int N = in_sizes[0] / 3;        // 100000
    const int E = in_sizes[3] / 2;        // 3200000

    float* Z   = (float*)d_ws;            // N*3 floats
    float* acc = Z + (size_t)N * 3;       // 3 floats: loss_sum, ang_sum, cnt

    hipMemsetAsync(d_ws, 0, ((size_t)N * 3 + 3) * sizeof(float), stream);

    const int block = 256;
    int egrid = (E + block - 1) / block;
    if (egrid > 2048) egrid = 2048;
    edge_scatter_kernel<<<egrid, block, 0, stream>>>(x, s, ei, Z, E);

    int ngrid = (N + block - 1) / block;
    node_reduce_kernel<<<ngrid, block, 0, stream>>>(y, Z, mask, acc, N);

    finalize_kernel<<<1, 1, 0, stream>>>(acc, out);
}

// Round 2
// 1011.583 us; speedup vs baseline: 1.0052x; 1.0052x over previous
//
#include <hip/hip_runtime.h>
#include <math.h>

// ---------------------------------------------------------------------------
// Edge scatter. For edge (a,b): c = (x[b]-x[a]) * (s[b]-s[a]) is identical for
// both endpoints (both factors flip sign), so compute once, add to both.
//
// FAST path: per-XCD replicas of Z + workgroup-scope relaxed atomics. These
// execute in the local XCD's L2 (TCC) instead of the device-coherent memory
// side. Correct because all atomics to replica r come only from XCD r (all
// waves of a workgroup share one CU -> one XCD), and the implicit L2
// writeback at kernel end publishes results to the reduce kernel.
// ---------------------------------------------------------------------------
template <bool XCD_LOCAL>
__global__ void edge_scatter_kernel(const float* __restrict__ x,
                                    const float* __restrict__ s,
                                    const int* __restrict__ ei,
                                    float* __restrict__ Z,
                                    int E, int rep_stride) {
    float* Zr = Z;
    if (XCD_LOCAL) {
        int xcc;
        asm volatile("s_getreg_b32 %0, hwreg(HW_REG_XCC_ID)" : "=s"(xcc));
        Zr = Z + (size_t)(xcc & 7) * rep_stride;
    }
    int i = blockIdx.x * blockDim.x + threadIdx.x;
    if (i >= E) return;
    int a = ei[i];
    int b = ei[i + E];
    float ds = s[b] - s[a];
    float cx = (x[3 * b + 0] - x[3 * a + 0]) * ds;
    float cy = (x[3 * b + 1] - x[3 * a + 1]) * ds;
    float cz = (x[3 * b + 2] - x[3 * a + 2]) * ds;
    if (XCD_LOCAL) {
        __hip_atomic_fetch_add(&Zr[3 * a + 0], cx, __ATOMIC_RELAXED, __HIP_MEMORY_SCOPE_WORKGROUP);
        __hip_atomic_fetch_add(&Zr[3 * a + 1], cy, __ATOMIC_RELAXED, __HIP_MEMORY_SCOPE_WORKGROUP);
        __hip_atomic_fetch_add(&Zr[3 * a + 2], cz, __ATOMIC_RELAXED, __HIP_MEMORY_SCOPE_WORKGROUP);
        __hip_atomic_fetch_add(&Zr[3 * b + 0], cx, __ATOMIC_RELAXED, __HIP_MEMORY_SCOPE_WORKGROUP);
        __hip_atomic_fetch_add(&Zr[3 * b + 1], cy, __ATOMIC_RELAXED, __HIP_MEMORY_SCOPE_WORKGROUP);
        __hip_atomic_fetch_add(&Zr[3 * b + 2], cz, __ATOMIC_RELAXED, __HIP_MEMORY_SCOPE_WORKGROUP);
    } else {
        atomicAdd(&Zr[3 * a + 0], cx);
        atomicAdd(&Zr[3 * a + 1], cy);
        atomicAdd(&Zr[3 * a + 2], cz);
        atomicAdd(&Zr[3 * b + 0], cx);
        atomicAdd(&Zr[3 * b + 1], cy);
        atomicAdd(&Zr[3 * b + 2], cz);
    }
}

// ---------------------------------------------------------------------------
// Per-node: sum replicas, cos(y, Z), masked reductions.
// ---------------------------------------------------------------------------
__global__ void node_reduce_kernel(const float* __restrict__ y,
                                   const float* __restrict__ Z,
                                   const unsigned char* __restrict__ mask,
                                   float* __restrict__ acc,
                                   int N, int nrep, int rep_stride) {
    int i = blockIdx.x * blockDim.x + threadIdx.x;
    float l = 0.f, a = 0.f, c = 0.f;
    if (i < N) {
        float zx = 0.f, zy = 0.f, zz = 0.f;
        for (int r = 0; r < nrep; ++r) {
            const float* Zr = Z + (size_t)r * rep_stride;
            zx += Zr[3 * i + 0];
            zy += Zr[3 * i + 1];
            zz += Zr[3 * i + 2];
        }
        float yx = y[3 * i + 0], yy = y[3 * i + 1], yz = y[3 * i + 2];
        float ny = sqrtf(yx * yx + yy * yy + yz * yz);
        float nz = sqrtf(zx * zx + zy * zy + zz * zz);
        float cosv = (yx * zx + yy * zy + yz * zz) / (ny * nz);
        float m = mask[i] ? 1.f : 0.f;
        l = m * (1.f - fabsf(cosv));
        float cc = fminf(fmaxf(cosv, -1.f), 1.f);
        a = m * acosf(cc) * 57.295779513082320876f;  // degrees
        c = m;
    }
    #pragma unroll
    for (int off = 32; off > 0; off >>= 1) {
        l += __shfl_down(l, off);
        a += __shfl_down(a, off);
        c += __shfl_down(c, off);
    }
    if ((threadIdx.x & 63) == 0) {
        atomicAdd(&acc[0], l);
        atomicAdd(&acc[1], a);
        atomicAdd(&acc[2], c);
    }
}

__global__ void finalize_kernel(const float* __restrict__ acc,
                                float* __restrict__ out) {
    float cnt = fmaxf(acc[2], 1.f);
    out[0] = acc[0] / cnt;   // loss
    out[1] = acc[1] / cnt;   // avg angle (degrees)
}

extern "C" void kernel_launch(void* const* d_in, const int* in_sizes, int n_in,
                              void* d_out, int out_size, void* d_ws, size_t ws_size,
                              hipStream_t stream) {
    const float*         x    = (const float*)d_in[0];
    const float*         y    = (const float*)d_in[1];
    const float*         s    = (const float*)d_in[2];
    const int*           ei   = (const int*)d_in[3];
    const unsigned char* mask = (const unsigned char*)d_in[4];
    float*               out  = (float*)d_out;

    const int N = in_sizes[0] / 3;        // 100000
    const int E = in_sizes[3] / 2;        // 3200000
    const int rep_stride = N * 3;

    // Decide replica count based on workspace size.
    const size_t need_fast = ((size_t)rep_stride * 8 + 3) * sizeof(float);
    const bool fast = ws_size >= need_fast;
    const int nrep = fast ? 8 : 1;

    float* Z   = (float*)d_ws;
    float* acc = Z + (size_t)rep_stride * nrep;

    hipMemsetAsync(d_ws, 0, ((size_t)rep_stride * nrep + 3) * sizeof(float), stream);

    const int block = 256;
    int egrid = (E + block - 1) / block;   // one thread per edge
    if (fast) {
        edge_scatter_kernel<true><<<egrid, block, 0, stream>>>(x, s, ei, Z, E, rep_stride);
    } else {
        edge_scatter_kernel<false><<<egrid, block, 0, stream>>>(x, s, ei, Z, E, rep_stride);
    }

    int ngrid = (N + block - 1) / block;
    node_reduce_kernel<<<ngrid, block, 0, stream>>>(y, Z, mask, acc, N, nrep, rep_stride);

    finalize_kernel<<<1, 1, 0, stream>>>(acc, out);
}

// Round 3
// 198.438 us; speedup vs baseline: 5.1240x; 5.0977x over previous
//
#include <hip/hip_runtime.h>
#include <math.h>

#define NC     10240   // nodes per chunk  -> LDS = NC*3*4 = 122880 B
#define BPER   25      // edge-slice blocks per chunk
#define EBLOCK 1024    // threads per scatter block

// ---------------------------------------------------------------------------
// Chunked edge scatter: block (chunk c, slice sl) streams its edge slice and
// accumulates contributions for nodes in [c*NC, c*NC+NC) into LDS (ds_add_f32
// atomics -- no global atomics). Partial chunk written non-atomically to ws.
// For edge (a,b): c = (x[b]-x[a]) * (s[b]-s[a]) is identical for both
// endpoints (both factors flip sign), so compute once, add to both.
// ---------------------------------------------------------------------------
__global__ __launch_bounds__(EBLOCK, 1)
void edge_chunk_kernel(const float* __restrict__ x,
                       const float* __restrict__ s,
                       const int* __restrict__ ei,
                       float* __restrict__ partials,
                       int E, int N) {
    extern __shared__ float lds[];           // NC*3 floats
    const int bid = blockIdx.x;
    const int c   = bid / BPER;
    const int sl  = bid - c * BPER;
    const int lo  = c * NC;
    const int hi  = min(lo + NC, N);

    for (int t = threadIdx.x; t < NC * 3; t += EBLOCK) lds[t] = 0.f;
    __syncthreads();

    const int  Q    = E >> 2;                // edge quads
    const int  qper = (Q + BPER - 1) / BPER;
    const int  qlo  = sl * qper;
    const int  qhi  = min(qlo + qper, Q);
    const int4* eiA = (const int4*)ei;       // sources
    const int4* eiB = (const int4*)(ei + E); // dests (E*4 bytes is 16B-aligned)

    for (int q = qlo + (int)threadIdx.x; q < qhi; q += EBLOCK) {
        int4 A = eiA[q];
        int4 B = eiB[q];
        #pragma unroll
        for (int j = 0; j < 4; ++j) {
            int a = (&A.x)[j];
            int b = (&B.x)[j];
            bool ha = (a >= lo) & (a < hi);
            bool hb = (b >= lo) & (b < hi);
            if (ha | hb) {
                float ds = s[b] - s[a];
                float cx = (x[3*b+0] - x[3*a+0]) * ds;
                float cy = (x[3*b+1] - x[3*a+1]) * ds;
                float cz = (x[3*b+2] - x[3*a+2]) * ds;
                if (ha) {
                    int la = (a - lo) * 3;
                    atomicAdd(&lds[la+0], cx);
                    atomicAdd(&lds[la+1], cy);
                    atomicAdd(&lds[la+2], cz);
                }
                if (hb) {
                    int lb = (b - lo) * 3;
                    atomicAdd(&lds[lb+0], cx);
                    atomicAdd(&lds[lb+1], cy);
                    atomicAdd(&lds[lb+2], cz);
                }
            }
        }
    }
    // scalar tail (E not divisible by 4), once per chunk
    if (sl == 0) {
        for (int e = (Q << 2) + (int)threadIdx.x; e < E; e += EBLOCK) {
            int a = ei[e], b = ei[e + E];
            bool ha = (a >= lo) & (a < hi);
            bool hb = (b >= lo) & (b < hi);
            if (ha | hb) {
                float ds = s[b] - s[a];
                float cx = (x[3*b+0] - x[3*a+0]) * ds;
                float cy = (x[3*b+1] - x[3*a+1]) * ds;
                float cz = (x[3*b+2] - x[3*a+2]) * ds;
                if (ha) { int la=(a-lo)*3; atomicAdd(&lds[la],cx); atomicAdd(&lds[la+1],cy); atomicAdd(&lds[la+2],cz); }
                if (hb) { int lb=(b-lo)*3; atomicAdd(&lds[lb],cx); atomicAdd(&lds[lb+1],cy); atomicAdd(&lds[lb+2],cz); }
            }
        }
    }
    __syncthreads();

    float4*       dst = (float4*)(partials + (size_t)bid * (NC * 3));
    const float4* src = (const float4*)lds;
    for (int t = threadIdx.x; t < (NC * 3) / 4; t += EBLOCK) dst[t] = src[t];
}

// ---------------------------------------------------------------------------
// Per-node: sum the BPER partials of this node's chunk, cos(y,Z), reductions.
// ---------------------------------------------------------------------------
__global__ void node_reduce_kernel(const float* __restrict__ y,
                                   const float* __restrict__ partials,
                                   const unsigned char* __restrict__ mask,
                                   float* __restrict__ acc, int N) {
    int i = blockIdx.x * blockDim.x + threadIdx.x;
    float l = 0.f, a = 0.f, cm = 0.f;
    if (i < N) {
        int c     = i / NC;
        int local = i - c * NC;
        const float* base = partials + (size_t)(c * BPER) * (NC * 3) + (size_t)local * 3;
        float zx = 0.f, zy = 0.f, zz = 0.f;
        #pragma unroll 5
        for (int p = 0; p < BPER; ++p) {
            const float* pp = base + (size_t)p * (NC * 3);
            zx += pp[0]; zy += pp[1]; zz += pp[2];
        }
        float yx = y[3*i+0], yy = y[3*i+1], yz = y[3*i+2];
        float ny = sqrtf(yx*yx + yy*yy + yz*yz);
        float nz = sqrtf(zx*zx + zy*zy + zz*zz);
        float cosv = (yx*zx + yy*zy + yz*zz) / (ny * nz);
        float m = mask[i] ? 1.f : 0.f;
        l = m * (1.f - fabsf(cosv));
        float cc = fminf(fmaxf(cosv, -1.f), 1.f);
        a = m * acosf(cc) * 57.295779513082320876f;  // degrees
        cm = m;
    }
    #pragma unroll
    for (int off = 32; off > 0; off >>= 1) {
        l  += __shfl_down(l, off);
        a  += __shfl_down(a, off);
        cm += __shfl_down(cm, off);
    }
    if ((threadIdx.x & 63) == 0) {
        atomicAdd(&acc[0], l);
        atomicAdd(&acc[1], a);
        atomicAdd(&acc[2], cm);
    }
}

__global__ void finalize_kernel(const float* __restrict__ acc,
                                float* __restrict__ out) {
    float cnt = fmaxf(acc[2], 1.f);
    out[0] = acc[0] / cnt;
    out[1] = acc[1] / cnt;
}

// ---------------------------------------------------------------------------
// Fallback (ws too small): plain global-atomic scatter (round-1 verified).
// ---------------------------------------------------------------------------
__global__ void edge_scatter_atomic(const float* __restrict__ x,
                                    const float* __restrict__ s,
                                    const int* __restrict__ ei,
                                    float* __restrict__ Z, int E) {
    int i = blockIdx.x * blockDim.x + threadIdx.x;
    if (i >= E) return;
    int a = ei[i], b = ei[i + E];
    float ds = s[b] - s[a];
    float cx = (x[3*b+0] - x[3*a+0]) * ds;
    float cy = (x[3*b+1] - x[3*a+1]) * ds;
    float cz = (x[3*b+2] - x[3*a+2]) * ds;
    atomicAdd(&Z[3*a+0], cx); atomicAdd(&Z[3*a+1], cy); atomicAdd(&Z[3*a+2], cz);
    atomicAdd(&Z[3*b+0], cx); atomicAdd(&Z[3*b+1], cy); atomicAdd(&Z[3*b+2], cz);
}

__global__ void node_reduce_simple(const float* __restrict__ y,
                                   const float* __restrict__ Z,
                                   const unsigned char* __restrict__ mask,
                                   float* __restrict__ acc, int N) {
    int i = blockIdx.x * blockDim.x + threadIdx.x;
    float l = 0.f, a = 0.f, cm = 0.f;
    if (i < N) {
        float zx = Z[3*i+0], zy = Z[3*i+1], zz = Z[3*i+2];
        float yx = y[3*i+0], yy = y[3*i+1], yz = y[3*i+2];
        float ny = sqrtf(yx*yx + yy*yy + yz*yz);
        float nz = sqrtf(zx*zx + zy*zy + zz*zz);
        float cosv = (yx*zx + yy*zy + yz*zz) / (ny * nz);
        float m = mask[i] ? 1.f : 0.f;
        l = m * (1.f - fabsf(cosv));
        float cc = fminf(fmaxf(cosv, -1.f), 1.f);
        a = m * acosf(cc) * 57.295779513082320876f;
        cm = m;
    }
    #pragma unroll
    for (int off = 32; off > 0; off >>= 1) {
        l += __shfl_down(l, off); a += __shfl_down(a, off); cm += __shfl_down(cm, off);
    }
    if ((threadIdx.x & 63) == 0) {
        atomicAdd(&acc[0], l); atomicAdd(&acc[1], a); atomicAdd(&acc[2], cm);
    }
}

extern "C" void kernel_launch(void* const* d_in, const int* in_sizes, int n_in,
                              void* d_out, int out_size, void* d_ws, size_t ws_size,
                              hipStream_t stream) {
    const float*         x    = (const float*)d_in[0];
    const float*         y    = (const float*)d_in[1];
    const float*         s    = (const float*)d_in[2];
    const int*           ei   = (const int*)d_in[3];
    const unsigned char* mask = (const unsigned char*)d_in[4];
    float*               out  = (float*)d_out;

    const int N = in_sizes[0] / 3;   // 100000
    const int E = in_sizes[3] / 2;   // 3200000

    const int nchunks = (N + NC - 1) / NC;                 // 10
    const size_t npart = (size_t)nchunks * BPER * (NC * 3); // floats
    const size_t need  = (npart + 3) * sizeof(float);

    if (ws_size >= need) {
        float* partials = (float*)d_ws;
        float* acc      = partials + npart;
        hipMemsetAsync(acc, 0, 3 * sizeof(float), stream);

        edge_chunk_kernel<<<nchunks * BPER, EBLOCK, NC * 3 * sizeof(float), stream>>>(
            x, s, ei, partials, E, N);

        int ngrid = (N + 255) / 256;
        node_reduce_kernel<<<ngrid, 256, 0, stream>>>(y, partials, mask, acc, N);
        finalize_kernel<<<1, 1, 0, stream>>>(acc, out);
    } else {
        float* Z   = (float*)d_ws;
        float* acc = Z + (size_t)N * 3;
        hipMemsetAsync(d_ws, 0, ((size_t)N * 3 + 3) * sizeof(float), stream);
        int egrid = (E + 255) / 256;
        edge_scatter_atomic<<<egrid, 256, 0, stream>>>(x, s, ei, Z, E);
        int ngrid = (N + 255) / 256;
        node_reduce_simple<<<ngrid, 256, 0, stream>>>(y, Z, mask, acc, N);
        finalize_kernel<<<1, 1, 0, stream>>>(acc, out);
    }
}

// Round 4
// 194.665 us; speedup vs baseline: 5.2233x; 1.0194x over previous
//
#include <hip/hip_runtime.h>
#include <math.h>

#define EBLOCK 1024

// ---------------------------------------------------------------------------
// Pre-pass: pack xs[i] = (x0, x1, x2, s) so each hit gathers 2 dwordx4 loads.
// Also zeroes the accumulator + ticket (harness poisons ws before timing).
// ---------------------------------------------------------------------------
__global__ void repack_kernel(const float* __restrict__ x,
                              const float* __restrict__ s,
                              float4* __restrict__ xs,
                              float* __restrict__ acc, int N) {
    int i = blockIdx.x * blockDim.x + threadIdx.x;
    if (i < N) xs[i] = make_float4(x[3 * i + 0], x[3 * i + 1], x[3 * i + 2], s[i]);
    if (i < 4) acc[i] = 0.f;   // acc[0..2] sums, acc[3] reinterpreted as ticket
}

// ---------------------------------------------------------------------------
// Chunked edge scatter. Edge (a,b): c = (x[b]-x[a]) * (s[b]-s[a]) identical
// for both endpoints. Accumulate into LDS (ds_add_f32), write partial chunk.
// nc/spc are runtime so one kernel serves all workspace tiers.
// ---------------------------------------------------------------------------
template <bool PACKED>
__global__ __launch_bounds__(EBLOCK, 1)
void edge_chunk_kernel(const float4* __restrict__ xs,
                       const float* __restrict__ x,
                       const float* __restrict__ s,
                       const int* __restrict__ ei,
                       float* __restrict__ partials,
                       int E, int nc, int spc) {
    extern __shared__ float lds[];             // nc*3 floats
    const int bid = blockIdx.x;
    const int c   = bid / spc;
    const int sl  = bid - c * spc;
    const int lo  = c * nc;
    const int nc3 = nc * 3;

    float4* l4 = (float4*)lds;
    for (int t = threadIdx.x; t < (nc3 >> 2); t += EBLOCK)
        l4[t] = make_float4(0.f, 0.f, 0.f, 0.f);
    __syncthreads();

    const int  Q    = E >> 2;
    const int  qper = (Q + spc - 1) / spc;
    const int  qlo  = sl * qper;
    const int  qhi  = min(qlo + qper, Q);
    const int4* eiA = (const int4*)ei;
    const int4* eiB = (const int4*)(ei + E);

    for (int q = qlo + (int)threadIdx.x; q < qhi; q += EBLOCK) {
        int4 A = eiA[q];
        int4 B = eiB[q];
        #pragma unroll
        for (int j = 0; j < 4; ++j) {
            int a = (&A.x)[j];
            int b = (&B.x)[j];
            unsigned ra = (unsigned)(a - lo);
            unsigned rb = (unsigned)(b - lo);
            bool ha = ra < (unsigned)nc;
            bool hb = rb < (unsigned)nc;
            if (ha | hb) {
                float cx, cy, cz;
                if (PACKED) {
                    float4 pa = xs[a];
                    float4 pb = xs[b];
                    float ds = pb.w - pa.w;
                    cx = (pb.x - pa.x) * ds;
                    cy = (pb.y - pa.y) * ds;
                    cz = (pb.z - pa.z) * ds;
                } else {
                    float ds = s[b] - s[a];
                    cx = (x[3*b+0] - x[3*a+0]) * ds;
                    cy = (x[3*b+1] - x[3*a+1]) * ds;
                    cz = (x[3*b+2] - x[3*a+2]) * ds;
                }
                if (ha) {
                    atomicAdd(&lds[ra*3+0], cx);
                    atomicAdd(&lds[ra*3+1], cy);
                    atomicAdd(&lds[ra*3+2], cz);
                }
                if (hb) {
                    atomicAdd(&lds[rb*3+0], cx);
                    atomicAdd(&lds[rb*3+1], cy);
                    atomicAdd(&lds[rb*3+2], cz);
                }
            }
        }
    }
    // scalar tail (E % 4 != 0), handled once per chunk
    int base4 = Q << 2;
    if (sl == 0 && base4 < E) {
        for (int e = base4 + (int)threadIdx.x; e < E; e += EBLOCK) {
            int a = ei[e], b = ei[e + E];
            unsigned ra = (unsigned)(a - lo);
            unsigned rb = (unsigned)(b - lo);
            bool ha = ra < (unsigned)nc;
            bool hb = rb < (unsigned)nc;
            if (ha | hb) {
                float ds, cx, cy, cz;
                if (PACKED) {
                    float4 pa = xs[a], pb = xs[b];
                    ds = pb.w - pa.w;
                    cx = (pb.x-pa.x)*ds; cy = (pb.y-pa.y)*ds; cz = (pb.z-pa.z)*ds;
                } else {
                    ds = s[b] - s[a];
                    cx = (x[3*b+0]-x[3*a+0])*ds; cy = (x[3*b+1]-x[3*a+1])*ds; cz = (x[3*b+2]-x[3*a+2])*ds;
                }
                if (ha) { atomicAdd(&lds[ra*3],cx); atomicAdd(&lds[ra*3+1],cy); atomicAdd(&lds[ra*3+2],cz); }
                if (hb) { atomicAdd(&lds[rb*3],cx); atomicAdd(&lds[rb*3+1],cy); atomicAdd(&lds[rb*3+2],cz); }
            }
        }
    }
    __syncthreads();

    float4* dst = (float4*)(partials + (size_t)bid * nc3);
    for (int t = threadIdx.x; t < (nc3 >> 2); t += EBLOCK) dst[t] = l4[t];
}

// ---------------------------------------------------------------------------
// Node pass fused with finalize (ticket-atomic last-block pattern).
// ---------------------------------------------------------------------------
__global__ void node_fused_kernel(const float* __restrict__ y,
                                  const float* __restrict__ partials,
                                  const unsigned char* __restrict__ mask,
                                  float* __restrict__ acc,
                                  float* __restrict__ out,
                                  int N, int nc, int spc) {
    int i = blockIdx.x * blockDim.x + threadIdx.x;
    float l = 0.f, a = 0.f, cm = 0.f;
    if (i < N) {
        int c     = i / nc;
        int local = i - c * nc;
        int nc3   = nc * 3;
        const float* base = partials + (size_t)(c * spc) * nc3 + (size_t)local * 3;
        float zx = 0.f, zy = 0.f, zz = 0.f;
        for (int p = 0; p < spc; ++p) {
            const float* pp = base + (size_t)p * nc3;
            zx += pp[0]; zy += pp[1]; zz += pp[2];
        }
        float yx = y[3*i+0], yy = y[3*i+1], yz = y[3*i+2];
        float ny = sqrtf(yx*yx + yy*yy + yz*yz);
        float nz = sqrtf(zx*zx + zy*zy + zz*zz);
        float cosv = (yx*zx + yy*zy + yz*zz) / (ny * nz);
        float m = mask[i] ? 1.f : 0.f;
        l  = m * (1.f - fabsf(cosv));
        float cc = fminf(fmaxf(cosv, -1.f), 1.f);
        a  = m * acosf(cc) * 57.295779513082320876f;   // degrees
        cm = m;
    }
    #pragma unroll
    for (int off = 32; off > 0; off >>= 1) {
        l  += __shfl_down(l, off);
        a  += __shfl_down(a, off);
        cm += __shfl_down(cm, off);
    }
    if ((threadIdx.x & 63) == 0) {
        atomicAdd(&acc[0], l);
        atomicAdd(&acc[1], a);
        atomicAdd(&acc[2], cm);
    }
    __syncthreads();   // drains vmcnt -> this block's atomics are globally visible
    if (threadIdx.x == 0) {
        __threadfence();
        unsigned int* ticket = (unsigned int*)&acc[3];
        unsigned int old = atomicAdd(ticket, 1u);
        if (old == gridDim.x - 1) {     // all blocks' adds complete
            float ls = atomicAdd(&acc[0], 0.f);
            float as = atomicAdd(&acc[1], 0.f);
            float cs = atomicAdd(&acc[2], 0.f);
            float cnt = fmaxf(cs, 1.f);
            out[0] = ls / cnt;
            out[1] = as / cnt;
        }
    }
}

// ---------------------------------------------------------------------------
// Tier-C fallback: global-atomic scatter (round-1 verified).
// ---------------------------------------------------------------------------
__global__ void edge_scatter_atomic(const float* __restrict__ x,
                                    const float* __restrict__ s,
                                    const int* __restrict__ ei,
                                    float* __restrict__ Z, int E) {
    int i = blockIdx.x * blockDim.x + threadIdx.x;
    if (i >= E) return;
    int a = ei[i], b = ei[i + E];
    float ds = s[b] - s[a];
    float cx = (x[3*b+0]-x[3*a+0])*ds;
    float cy = (x[3*b+1]-x[3*a+1])*ds;
    float cz = (x[3*b+2]-x[3*a+2])*ds;
    atomicAdd(&Z[3*a+0],cx); atomicAdd(&Z[3*a+1],cy); atomicAdd(&Z[3*a+2],cz);
    atomicAdd(&Z[3*b+0],cx); atomicAdd(&Z[3*b+1],cy); atomicAdd(&Z[3*b+2],cz);
}

__global__ void node_simple_kernel(const float* __restrict__ y,
                                   const float* __restrict__ Z,
                                   const unsigned char* __restrict__ mask,
                                   float* __restrict__ acc,
                                   float* __restrict__ out, int N) {
    int i = blockIdx.x * blockDim.x + threadIdx.x;
    float l = 0.f, a = 0.f, cm = 0.f;
    if (i < N) {
        float zx = Z[3*i+0], zy = Z[3*i+1], zz = Z[3*i+2];
        float yx = y[3*i+0], yy = y[3*i+1], yz = y[3*i+2];
        float ny = sqrtf(yx*yx + yy*yy + yz*yz);
        float nz = sqrtf(zx*zx + zy*zy + zz*zz);
        float cosv = (yx*zx + yy*zy + yz*zz) / (ny * nz);
        float m = mask[i] ? 1.f : 0.f;
        l  = m * (1.f - fabsf(cosv));
        float cc = fminf(fmaxf(cosv, -1.f), 1.f);
        a  = m * acosf(cc) * 57.295779513082320876f;
        cm = m;
    }
    #pragma unroll
    for (int off = 32; off > 0; off >>= 1) {
        l += __shfl_down(l, off); a += __shfl_down(a, off); cm += __shfl_down(cm, off);
    }
    if ((threadIdx.x & 63) == 0) {
        atomicAdd(&acc[0], l); atomicAdd(&acc[1], a); atomicAdd(&acc[2], cm);
    }
    __syncthreads();
    if (threadIdx.x == 0) {
        __threadfence();
        unsigned int* ticket = (unsigned int*)&acc[3];
        unsigned int old = atomicAdd(ticket, 1u);
        if (old == gridDim.x - 1) {
            float ls = atomicAdd(&acc[0], 0.f);
            float as = atomicAdd(&acc[1], 0.f);
            float cs = atomicAdd(&acc[2], 0.f);
            float cnt = fmaxf(cs, 1.f);
            out[0] = ls / cnt;
            out[1] = as / cnt;
        }
    }
}

extern "C" void kernel_launch(void* const* d_in, const int* in_sizes, int n_in,
                              void* d_out, int out_size, void* d_ws, size_t ws_size,
                              hipStream_t stream) {
    const float*         x    = (const float*)d_in[0];
    const float*         y    = (const float*)d_in[1];
    const float*         s    = (const float*)d_in[2];
    const int*           ei   = (const int*)d_in[3];
    const unsigned char* mask = (const unsigned char*)d_in[4];
    float*               out  = (float*)d_out;

    const int N = in_sizes[0] / 3;   // 100000
    const int E = in_sizes[3] / 2;   // 3200000

    // Tier A: packed xs + NC=12800 (150 KB LDS), 8 chunks x 32 slices.
    {
        const int nc = 12800, spc = 32;
        const int chunks = (N + nc - 1) / nc;
        const int grid   = chunks * spc;
        const size_t np  = (size_t)grid * nc * 3;                    // partial floats
        const size_t need = (size_t)N * 16 + 16 + np * sizeof(float);
        if (ws_size >= need) {
            float4* xs       = (float4*)d_ws;
            float*  acc      = (float*)(xs + N);
            float*  partials = acc + 4;
            repack_kernel<<<(N + 255) / 256, 256, 0, stream>>>(x, s, xs, acc, N);
            edge_chunk_kernel<true><<<grid, EBLOCK, nc * 3 * sizeof(float), stream>>>(
                xs, x, s, ei, partials, E, nc, spc);
            node_fused_kernel<<<(N + 255) / 256, 256, 0, stream>>>(
                y, partials, mask, acc, out, N, nc, spc);
            return;
        }
    }
    // Tier B: round-3-proven footprint, NC=10240 (120 KB LDS), 10 x 25.
    {
        const int nc = 10240, spc = 25;
        const int chunks = (N + nc - 1) / nc;
        const int grid   = chunks * spc;
        const size_t np  = (size_t)grid * nc * 3;
        const size_t need = 16 + np * sizeof(float);
        if (ws_size >= need) {
            float* acc      = (float*)d_ws;
            float* partials = acc + 4;
            hipMemsetAsync(acc, 0, 16, stream);
            edge_chunk_kernel<false><<<grid, EBLOCK, nc * 3 * sizeof(float), stream>>>(
                nullptr, x, s, ei, partials, E, nc, spc);
            node_fused_kernel<<<(N + 255) / 256, 256, 0, stream>>>(
                y, partials, mask, acc, out, N, nc, spc);
            return;
        }
    }
    // Tier C: global atomics.
    {
        float* Z   = (float*)d_ws;
        float* acc = Z + (size_t)N * 3;
        hipMemsetAsync(d_ws, 0, ((size_t)N * 3 + 4) * sizeof(float), stream);
        edge_scatter_atomic<<<(E + 255) / 256, 256, 0, stream>>>(x, s, ei, Z, E);
        node_simple_kernel<<<(N + 255) / 256, 256, 0, stream>>>(y, Z, mask, acc, out, N);
    }
}